// Round 1
// baseline (927.933 us; speedup 1.0000x reference)
//
#include <hip/hip_runtime.h>

// Problem constants
#define HDIM   64
#define VDIM   64
#define INNERD 16
#define LRC    0.01f
#define EPSV   1e-5f
#define TSTEPS 1023
// gradient scale: dL/dy = 2*(y-v)/64 = d/32 ; combined with LR => LR/32
#define GAMMA  (LRC / 32.0f)

// workspace layout (float offsets)
#define WS_HS 0       // 64*64 hs table
#define WS_G  4096    // 64*64 gram
#define WS_Z0 8192    // 64*16 initial Ztilde = hs@w1 + b1

// ---------------- kernel A: hs table (per-token embed->FFN->LN) ----------------
__global__ void hs_kernel(const float* __restrict__ embed,
                          const float* __restrict__ ffw1, const float* __restrict__ ffb1,
                          const float* __restrict__ ffw2, const float* __restrict__ ffb2,
                          const float* __restrict__ lng,  const float* __restrict__ lnb,
                          float* __restrict__ ws) {
    __shared__ float e[64];
    __shared__ float a1[128];
    __shared__ float h[64];
    __shared__ float stats[2];
    int w = blockIdx.x;
    int tid = threadIdx.x;
    if (tid < 64) e[tid] = embed[w * 64 + tid];
    __syncthreads();
    // z1_i = e @ ff_w1 + ff_b1   (i in [0,128))
    float z1 = ffb1[tid];
    for (int x = 0; x < 64; ++x) z1 += e[x] * ffw1[x * 128 + tid];
    a1[tid] = fmaxf(z1, 0.0f);
    __syncthreads();
    if (tid < 64) {
        float f = ffb2[tid];
        for (int i = 0; i < 128; ++i) f += a1[i] * ffw2[i * 64 + tid];
        h[tid] = e[tid] + f;
    }
    __syncthreads();
    if (tid == 0) {
        float mu = 0.0f;
        for (int x = 0; x < 64; ++x) mu += h[x];
        mu *= (1.0f / 64.0f);
        float var = 0.0f;
        for (int x = 0; x < 64; ++x) { float d = h[x] - mu; var += d * d; }
        var *= (1.0f / 64.0f);
        stats[0] = mu;
        stats[1] = 1.0f / sqrtf(var + EPSV);
    }
    __syncthreads();
    if (tid < 64) {
        ws[WS_HS + w * 64 + tid] = (h[tid] - stats[0]) * stats[1] * lng[tid] + lnb[tid];
    }
}

// ---------------- kernel B: Gram matrix + Ztilde0 ----------------
__global__ void gz_kernel(const float* __restrict__ w1, const float* __restrict__ b1,
                          float* __restrict__ ws) {
    __shared__ float row[64];
    int w = blockIdx.x, tid = threadIdx.x;
    row[tid] = ws[WS_HS + w * 64 + tid];
    __syncthreads();
    float g = 0.0f;
    for (int x = 0; x < 64; ++x) g += row[x] * ws[WS_HS + tid * 64 + x];
    ws[WS_G + w * 64 + tid] = g;
    if (tid < 16) {
        float z = b1[tid];
        for (int x = 0; x < 64; ++x) z += row[x] * w1[x * 16 + tid];
        ws[WS_Z0 + w * 16 + tid] = z;
    }
}

// ---------------- main kernel: per-batch sequential TTT scan ----------------
// one wave (64 lanes) per batch; lane h owns W2[:,h], b2_h; lane r owns Ztilde row r (regs)
__launch_bounds__(64, 1)
__global__ void ttt_kernel(const int* __restrict__ seq,
                           const float* __restrict__ w2, const float* __restrict__ b2,
                           const float* __restrict__ outw, const float* __restrict__ outb,
                           const float* __restrict__ ws, float* __restrict__ out) {
    __shared__ float hs[64 * 64];
    __shared__ float G[64 * 64];
    __shared__ int   sq[2048];
    __shared__ __align__(16) float pT[16 * 68];   // p scattered [j][h], row stride 68 floats (272B, 16B-aligned)
    __shared__ __align__(16) float dabuf[16];
    __shared__ float ctxbuf[64];

    const int b = blockIdx.x;
    const int lane = threadIdx.x;

    // stage tables + this batch's token row
    for (int m = 0; m < 64; ++m) hs[m * 64 + lane] = ws[WS_HS + m * 64 + lane];
    for (int m = 0; m < 64; ++m) G[m * 64 + lane]  = ws[WS_G + m * 64 + lane];
    for (int m = 0; m < 32; ++m) sq[m * 64 + lane] = seq[b * 2048 + m * 64 + lane];

    float W2c[16], Zr[16];
#pragma unroll
    for (int j = 0; j < 16; ++j) W2c[j] = w2[j * 64 + lane];
    float b2v = b2[lane];
#pragma unroll
    for (int j = 0; j < 16; ++j) Zr[j] = ws[WS_Z0 + lane * 16 + j];
    __syncthreads();

    int tk = sq[0];
    int tv = sq[1];
    float z[16];
#pragma unroll
    for (int j = 0; j < 16; ++j) z[j] = __shfl(Zr[j], tk);   // z_0 = Ztilde0[tk0]
    float vv = hs[tv * 64 + lane];

    for (int t = 0; t < TSTEPS; ++t) {
        // ---- prefetch next step's tokens / rows (reads Ztilde_t BEFORE this step's update) ----
        const int kidx = (t < TSTEPS - 1) ? (2 * t + 2) : 2047;  // last prefetch = final query token
        const int tk1 = sq[kidx];
        const int tv1 = sq[2 * t + 3];
        float zpre[16];
#pragma unroll
        for (int j = 0; j < 16; ++j) zpre[j] = __shfl(Zr[j], tk1);
        const float vnext = hs[tv1 * 64 + lane];
        const float gcol  = G[tk * 64 + lane];   // G[lane][tk] (symmetric) -> Zrow update coeff
        const float gsc   = G[tk * 64 + tk1];    // G[tk1][tk] -> z correction coeff

        // ---- forward ----
        float a[16], mk[16];
#pragma unroll
        for (int j = 0; j < 16; ++j) {
            a[j]  = fmaxf(z[j], 0.0f);
            mk[j] = (z[j] > 0.0f) ? 1.0f : 0.0f;
        }
        float y0 = 0.f, y1 = 0.f, y2 = 0.f, y3 = 0.f;
#pragma unroll
        for (int j = 0; j < 16; j += 4) {
            y0 += a[j] * W2c[j];
            y1 += a[j + 1] * W2c[j + 1];
            y2 += a[j + 2] * W2c[j + 2];
            y3 += a[j + 3] * W2c[j + 3];
        }
        const float y = b2v + ((y0 + y1) + (y2 + y3));
        const float d = y - vv;                 // raw diff; /32 and LR folded into constants

        // ---- scatter p_j(h) = W2[j][h]*d  (pre-update W2) ----
#pragma unroll
        for (int j = 0; j < 16; ++j) pT[j * 68 + lane] = W2c[j] * d;

        // ---- local updates (W2 col, b2) ----
        const float sd = GAMMA * d;             // LR/32 * d
        b2v -= sd;
#pragma unroll
        for (int j = 0; j < 16; ++j) W2c[j] -= sd * a[j];

        __syncthreads();  // order scatter-writes vs row-fold reads (single wave: cheap)

        // ---- reduce: lanes 0..15 fold full 64-wide rows -> da'[j] ----
        if (lane < 16) {
            const float4* rowp = (const float4*)(pT + lane * 68);
            float s0 = 0.f, s1 = 0.f, s2 = 0.f, s3 = 0.f;
#pragma unroll
            for (int c = 0; c < 16; c += 4) {
                float4 r0 = rowp[c], r1 = rowp[c + 1], r2 = rowp[c + 2], r3 = rowp[c + 3];
                s0 += (r0.x + r0.y) + (r0.z + r0.w);
                s1 += (r1.x + r1.y) + (r1.z + r1.w);
                s2 += (r2.x + r2.y) + (r2.z + r2.w);
                s3 += (r3.x + r3.y) + (r3.z + r3.w);
            }
            dabuf[lane] = (s0 + s1) + (s2 + s3);
        }
        __syncthreads();

        float da[16];
        {
            const float4* dp = (const float4*)dabuf;
            float4 q0 = dp[0], q1 = dp[1], q2 = dp[2], q3 = dp[3];
            da[0] = q0.x;  da[1] = q0.y;  da[2] = q0.z;  da[3] = q0.w;
            da[4] = q1.x;  da[5] = q1.y;  da[6] = q1.z;  da[7] = q1.w;
            da[8] = q2.x;  da[9] = q2.y;  da[10] = q2.z; da[11] = q2.w;
            da[12] = q3.x; da[13] = q3.y; da[14] = q3.z; da[15] = q3.w;
        }

        // ---- Ztilde rank-1 update + corrected next z ----
        const float cr = GAMMA * gcol + GAMMA;   // gamma*(G[r][tk]+1)
        const float cz = GAMMA * gsc + GAMMA;    // gamma*(G[tk1][tk]+1)
#pragma unroll
        for (int j = 0; j < 16; ++j) {
            const float dz = mk[j] * da[j];      // masked, unscaled (gamma carries /32*LR)
            Zr[j] -= cr * dz;
            z[j] = zpre[j] - cz * dz;
        }

        vv = vnext;
        tk = tk1;
        tv = tv1;
    }

    // ---- final eval: z already = Ztilde_final[t_q]; ctx_h = relu(z)@W2_f + b2_f ----
    float ctx = b2v;
#pragma unroll
    for (int j = 0; j < 16; ++j) ctx += fmaxf(z[j], 0.0f) * W2c[j];
    ctxbuf[lane] = ctx;
    __syncthreads();

    // out[b][v] = ctx @ out_w + out_b   (lane = v)
    float o = outb[lane];
    for (int hh = 0; hh < 64; ++hh) o += ctxbuf[hh] * outw[hh * 64 + lane];
    out[b * 64 + lane] = o;
}

// ---------------- launcher ----------------
extern "C" void kernel_launch(void* const* d_in, const int* in_sizes, int n_in,
                              void* d_out, int out_size, void* d_ws, size_t ws_size,
                              hipStream_t stream) {
    const int*   seq   = (const int*)d_in[0];
    const float* embed = (const float*)d_in[1];
    const float* ffw1  = (const float*)d_in[2];
    const float* ffb1  = (const float*)d_in[3];
    const float* ffw2  = (const float*)d_in[4];
    const float* ffb2  = (const float*)d_in[5];
    const float* lng   = (const float*)d_in[6];
    const float* lnb   = (const float*)d_in[7];
    const float* w1    = (const float*)d_in[8];
    const float* b1    = (const float*)d_in[9];
    const float* w2    = (const float*)d_in[10];
    const float* b2    = (const float*)d_in[11];
    const float* outw  = (const float*)d_in[12];
    const float* outb  = (const float*)d_in[13];
    float* ws  = (float*)d_ws;
    float* out = (float*)d_out;

    hipLaunchKernelGGL(hs_kernel, dim3(64), dim3(128), 0, stream,
                       embed, ffw1, ffb1, ffw2, ffb2, lng, lnb, ws);
    hipLaunchKernelGGL(gz_kernel, dim3(64), dim3(64), 0, stream, w1, b1, ws);
    hipLaunchKernelGGL(ttt_kernel, dim3(256), dim3(64), 0, stream,
                       seq, w2, b2, outw, outb, ws, out);
}

// Round 2
// 794.273 us; speedup vs baseline: 1.1683x; 1.1683x over previous
//
#include <hip/hip_runtime.h>

// Problem constants
#define TSTEPS 1023
#define GAMMA  (0.01f / 32.0f)   // LR * (2/64)/2 folded: dL/dy = 2(y-v)/64 = d/32
#define EPSV   1e-5f

// workspace layout (float offsets)
#define WS_HS 0       // 64*64 hs table
#define WS_G  4096    // 64*64 gram
#define WS_Z0 8192    // 64*16 initial Ztilde = hs@w1 + b1

__device__ __forceinline__ float rdlane(float v, int lane) {
    return __int_as_float(__builtin_amdgcn_readlane(__float_as_int(v), lane));
}

// ---------------- kernel A: hs table (per-token embed->FFN->LN) ----------------
__global__ void hs_kernel(const float* __restrict__ embed,
                          const float* __restrict__ ffw1, const float* __restrict__ ffb1,
                          const float* __restrict__ ffw2, const float* __restrict__ ffb2,
                          const float* __restrict__ lng,  const float* __restrict__ lnb,
                          float* __restrict__ ws) {
    __shared__ float e[64];
    __shared__ float a1[128];
    int w = blockIdx.x;
    int tid = threadIdx.x;
    if (tid < 64) e[tid] = embed[w * 64 + tid];
    __syncthreads();
    float z1 = ffb1[tid];
    for (int x = 0; x < 64; ++x) z1 += e[x] * ffw1[x * 128 + tid];
    a1[tid] = fmaxf(z1, 0.0f);
    __syncthreads();
    if (tid < 64) {
        float f = ffb2[tid];
        for (int i = 0; i < 128; ++i) f += a1[i] * ffw2[i * 64 + tid];
        float hv = e[tid] + f;
        // wave reductions for LN stats (tid<64 == full wave 0)
        float s = hv;
#pragma unroll
        for (int m = 32; m >= 1; m >>= 1) s += __shfl_xor(s, m);
        float mu = s * (1.0f / 64.0f);
        float dv = hv - mu;
        float vs = dv * dv;
#pragma unroll
        for (int m = 32; m >= 1; m >>= 1) vs += __shfl_xor(vs, m);
        float rstd = 1.0f / sqrtf(vs * (1.0f / 64.0f) + EPSV);
        ws[WS_HS + w * 64 + tid] = dv * rstd * lng[tid] + lnb[tid];
    }
}

// ---------------- kernel B: Gram matrix + Ztilde0 ----------------
__global__ void gz_kernel(const float* __restrict__ w1, const float* __restrict__ b1,
                          float* __restrict__ ws) {
    __shared__ float row[64];
    int w = blockIdx.x, tid = threadIdx.x;
    row[tid] = ws[WS_HS + w * 64 + tid];
    __syncthreads();
    float g = 0.0f;
    for (int x = 0; x < 64; ++x) g += row[x] * ws[WS_HS + tid * 64 + x];
    ws[WS_G + w * 64 + tid] = g;
    if (tid < 16) {
        float z = b1[tid];
        for (int x = 0; x < 64; ++x) z += row[x] * w1[x * 16 + tid];
        ws[WS_Z0 + w * 16 + tid] = z;
    }
}

// ---------------- main kernel: per-batch sequential TTT scan ----------------
// one wave (64 lanes) per batch. lane h owns W2[:,h], b2_h, and Ztilde row h
// (regs, mirrored to LDS for the broadcast read). No barriers in the loop:
// single wave + in-order DS pipe provide all ordering.
__launch_bounds__(64, 1)
__global__ void ttt_kernel(const int* __restrict__ seq,
                           const float* __restrict__ w2, const float* __restrict__ b2i,
                           const float* __restrict__ outw, const float* __restrict__ outb,
                           const float* __restrict__ ws, float* __restrict__ out) {
    __shared__ float hs[64 * 64];
    __shared__ float G[64 * 64];
    __shared__ int   sq[2048];
    __shared__ __align__(16) float Z[64 * 20];   // row stride 20 floats: conflict-free b128 writes
    __shared__ float ctxbuf[64];

    const int b    = blockIdx.x;
    const int lane = threadIdx.x;

    {   // vectorized staging
        float4*       hv = (float4*)hs;
        const float4* sv = (const float4*)(ws + WS_HS);
#pragma unroll
        for (int m = 0; m < 16; ++m) hv[m * 64 + lane] = sv[m * 64 + lane];
        float4*       gv = (float4*)G;
        const float4* gs = (const float4*)(ws + WS_G);
#pragma unroll
        for (int m = 0; m < 16; ++m) gv[m * 64 + lane] = gs[m * 64 + lane];
        int4*       qv = (int4*)sq;
        const int4* qs = (const int4*)(seq + b * 2048);
#pragma unroll
        for (int m = 0; m < 8; ++m) qv[m * 64 + lane] = qs[m * 64 + lane];
    }

    float W2c[16], Zr[16];
#pragma unroll
    for (int j = 0; j < 16; ++j) W2c[j] = w2[j * 64 + lane];
    float b2v = b2i[lane];
    {
        const float4* z0 = (const float4*)(ws + WS_Z0 + lane * 16);
        float4 u0 = z0[0], u1 = z0[1], u2 = z0[2], u3 = z0[3];
        Zr[0] = u0.x;  Zr[1] = u0.y;  Zr[2] = u0.z;  Zr[3] = u0.w;
        Zr[4] = u1.x;  Zr[5] = u1.y;  Zr[6] = u1.z;  Zr[7] = u1.w;
        Zr[8] = u2.x;  Zr[9] = u2.y;  Zr[10] = u2.z; Zr[11] = u2.w;
        Zr[12] = u3.x; Zr[13] = u3.y; Zr[14] = u3.z; Zr[15] = u3.w;
        float4* zr = (float4*)(Z + lane * 20);
        zr[0] = u0; zr[1] = u1; zr[2] = u2; zr[3] = u3;
    }
    __syncthreads();

    int tk = sq[0];
    float z[16];
    {
        const float4* zp = (const float4*)(Z + tk * 20);
        float4 u0 = zp[0], u1 = zp[1], u2 = zp[2], u3 = zp[3];
        z[0] = u0.x;  z[1] = u0.y;  z[2] = u0.z;  z[3] = u0.w;
        z[4] = u1.x;  z[5] = u1.y;  z[6] = u1.z;  z[7] = u1.w;
        z[8] = u2.x;  z[9] = u2.y;  z[10] = u2.z; z[11] = u2.w;
        z[12] = u3.x; z[13] = u3.y; z[14] = u3.z; z[15] = u3.w;
    }
    float vv = hs[sq[1] * 64 + lane];

    const bool s5  = (lane & 32) != 0;
    const bool s4  = (lane & 16) != 0;
    const bool s3  = (lane & 8)  != 0;
    const bool s2b = (lane & 4)  != 0;

    for (int t = 0; t < TSTEPS; ++t) {
        const bool last = (t == TSTEPS - 1);
        const int  base = last ? 2046 : (2 * t + 2);
        const int2 pr   = *(const int2*)(sq + base);
        const int  tkn  = last ? pr.y : pr.x;   // last iter: final query token sq[2047]
        const int  tvn  = pr.y;

        // ---- early off-chain loads (consumed ~300 cyc later) ----
        const float4* zp = (const float4*)(Z + tkn * 20);   // reads Z_{t-1}[tkn] (pre-update)
        const float4 e0 = zp[0], e1 = zp[1], e2 = zp[2], e3 = zp[3];
        const float vnext = hs[tvn * 64 + lane];
        const float cr = GAMMA * G[tk * 64 + lane] + GAMMA;  // gamma*(G[lane][tk]+1)
        const float cz = GAMMA * G[tk * 64 + tkn] + GAMMA;   // gamma*(G[tkn][tk]+1)

        // ---- forward ----
        float a[16], mk[16];
#pragma unroll
        for (int j = 0; j < 16; ++j) {
            a[j]  = fmaxf(z[j], 0.0f);
            mk[j] = (z[j] > 0.0f) ? 1.0f : 0.0f;
        }
        float y0 = 0.f, y1 = 0.f, y2 = 0.f, y3 = 0.f;
#pragma unroll
        for (int j = 0; j < 16; j += 4) {
            y0 += a[j] * W2c[j];
            y1 += a[j + 1] * W2c[j + 1];
            y2 += a[j + 2] * W2c[j + 2];
            y3 += a[j + 3] * W2c[j + 3];
        }
        const float y = b2v + ((y0 + y1) + (y2 + y3));
        const float d = y - vv;

        // ---- p (pre-update W2), then local W2/b2 update ----
        float p[16];
#pragma unroll
        for (int j = 0; j < 16; ++j) p[j] = W2c[j] * d;
        const float sd = GAMMA * d;
        b2v -= sd;
#pragma unroll
        for (int j = 0; j < 16; ++j) W2c[j] -= sd * a[j];

        // ---- reduction: fold 16 values over 64 lanes, no LDS, no barrier ----
        float q[8];
#pragma unroll
        for (int j = 0; j < 8; ++j) {
            const float keep = s5 ? p[j + 8] : p[j];
            const float give = s5 ? p[j]     : p[j + 8];
            q[j] = keep + __shfl_xor(give, 32);
        }
        float r[4];
#pragma unroll
        for (int j = 0; j < 4; ++j) {
            const float keep = s4 ? q[j + 4] : q[j];
            const float give = s4 ? q[j]     : q[j + 4];
            r[j] = keep + __shfl_xor(give, 16);
        }
        float sfold[2];
#pragma unroll
        for (int j = 0; j < 2; ++j) {
            const float keep = s3 ? r[j + 2] : r[j];
            const float give = s3 ? r[j]     : r[j + 2];
            sfold[j] = keep + __shfl_xor(give, 8);
        }
        float u;
        {
            const float keep = s2b ? sfold[1] : sfold[0];
            const float give = s2b ? sfold[0] : sfold[1];
            u = keep + __shfl_xor(give, 4);
        }
        u += __shfl_xor(u, 2);
        u += __shfl_xor(u, 1);
        // now lane l holds da[(l>>2)&15]

        // ---- apply: dz, Ztilde row update (regs), next-z correction ----
        const float zq[16] = {e0.x, e0.y, e0.z, e0.w, e1.x, e1.y, e1.z, e1.w,
                              e2.x, e2.y, e2.z, e2.w, e3.x, e3.y, e3.z, e3.w};
#pragma unroll
        for (int j = 0; j < 16; ++j) {
            const float da = rdlane(u, 4 * j);
            const float dz = mk[j] * da;
            Zr[j] -= cr * dz;
            z[j] = zq[j] - cz * dz;
        }
        // commit this lane's Ztilde row to LDS (off-chain; DS pipe in-order)
        float4* zw = (float4*)(Z + lane * 20);
        zw[0] = make_float4(Zr[0], Zr[1], Zr[2], Zr[3]);
        zw[1] = make_float4(Zr[4], Zr[5], Zr[6], Zr[7]);
        zw[2] = make_float4(Zr[8], Zr[9], Zr[10], Zr[11]);
        zw[3] = make_float4(Zr[12], Zr[13], Zr[14], Zr[15]);

        vv = vnext;
        tk = tkn;
    }

    // ---- final eval: z = Ztilde_final[q_token]; ctx = relu(z)@W2_f + b2_f ----
    float ctx = b2v;
#pragma unroll
    for (int j = 0; j < 16; ++j) ctx += fmaxf(z[j], 0.0f) * W2c[j];
    ctxbuf[lane] = ctx;
    __syncthreads();

    float o = outb[lane];
    for (int hh = 0; hh < 64; ++hh) o += ctxbuf[hh] * outw[hh * 64 + lane];
    out[b * 64 + lane] = o;
}

// ---------------- launcher ----------------
extern "C" void kernel_launch(void* const* d_in, const int* in_sizes, int n_in,
                              void* d_out, int out_size, void* d_ws, size_t ws_size,
                              hipStream_t stream) {
    const int*   seq   = (const int*)d_in[0];
    const float* embed = (const float*)d_in[1];
    const float* ffw1  = (const float*)d_in[2];
    const float* ffb1  = (const float*)d_in[3];
    const float* ffw2  = (const float*)d_in[4];
    const float* ffb2  = (const float*)d_in[5];
    const float* lng   = (const float*)d_in[6];
    const float* lnb   = (const float*)d_in[7];
    const float* w1    = (const float*)d_in[8];
    const float* b1    = (const float*)d_in[9];
    const float* w2    = (const float*)d_in[10];
    const float* b2    = (const float*)d_in[11];
    const float* outw  = (const float*)d_in[12];
    const float* outb  = (const float*)d_in[13];
    float* ws  = (float*)d_ws;
    float* out = (float*)d_out;

    hipLaunchKernelGGL(hs_kernel, dim3(64), dim3(128), 0, stream,
                       embed, ffw1, ffb1, ffw2, ffb2, lng, lnb, ws);
    hipLaunchKernelGGL(gz_kernel, dim3(64), dim3(64), 0, stream, w1, b1, ws);
    hipLaunchKernelGGL(ttt_kernel, dim3(256), dim3(64), 0, stream,
                       seq, w2, b2, outw, outb, ws, out);
}